// Round 4
// baseline (620.375 us; speedup 1.0000x reference)
//
#include <hip/hip_runtime.h>

// ---------------------------------------------------------------------------
// Fused self-attention, B=8 N=4096 D=256, f32 in/out, bf16 MFMA internally.
// ws: Qs bf16 [B*N][256] @0 (pre-scaled by log2e/16)
//     Kb bf16 [B*N][256] @16MB
//     VT bf16 [B][256][N] @32MB
// ---------------------------------------------------------------------------

typedef __attribute__((ext_vector_type(8))) short short8;   // 8 bf16 = 4 VGPR
typedef __attribute__((ext_vector_type(4))) float f32x4;

#define MFMA16(A, B, C) __builtin_amdgcn_mfma_f32_16x16x32_bf16(A, B, C, 0, 0, 0)

__device__ __forceinline__ unsigned short f2bf(float f) {
  union { float f; unsigned u; } v; v.f = f;
  unsigned r = v.u + 0x7FFFu + ((v.u >> 16) & 1u);   // RNE
  return (unsigned short)(r >> 16);
}

__device__ __forceinline__ ushort4 pack4(float4 v) {
  ushort4 r;
  r.x = f2bf(v.x); r.y = f2bf(v.y); r.z = f2bf(v.z); r.w = f2bf(v.w);
  return r;
}

__device__ __forceinline__ void gload_lds16(const void* g, void* l) {
  __builtin_amdgcn_global_load_lds(
      (const __attribute__((address_space(1))) void*)g,
      (__attribute__((address_space(3))) void*)l, 16, 0, 0);
}

// DPP rotate within 16-lane rows (VALU pipe; ctrl must be literal).
template <int CTRL>
__device__ __forceinline__ float dpp_ror(float x) {
  return __int_as_float(
      __builtin_amdgcn_update_dpp(0, __float_as_int(x), CTRL, 0xf, 0xf, true));
}
__device__ __forceinline__ float red16_max(float x) {
  x = fmaxf(x, dpp_ror<0x128>(x));  // row_ror:8
  x = fmaxf(x, dpp_ror<0x124>(x));  // row_ror:4
  x = fmaxf(x, dpp_ror<0x122>(x));  // row_ror:2
  x = fmaxf(x, dpp_ror<0x121>(x));  // row_ror:1
  return x;
}
__device__ __forceinline__ float red16_sum(float x) {
  x += dpp_ror<0x128>(x);
  x += dpp_ror<0x124>(x);
  x += dpp_ror<0x122>(x);
  x += dpp_ror<0x121>(x);
  return x;
}

// --------------------------- Projection GEMM ------------------------------
// C[m][n] = A[m]·B[n] (+bias); 128x128 tile, BK=64, 4 waves each [32 m][128 n].
// MODE 0: A=x(tok), B=W(e<512) -> Qs (scaled) / Kb.   grid (4, 256)
// MODE 1: A=W+512 (d), B=x(tok) -> VT[b][d][n].       grid (2, 256)
template <int MODE>
__global__ __launch_bounds__(256)
void proj_kernel(const float* __restrict__ A, const float* __restrict__ Bm,
                 const float* __restrict__ bias,
                 unsigned short* __restrict__ Qs, unsigned short* __restrict__ Kb,
                 unsigned short* __restrict__ VT) {
  __shared__ __align__(16) unsigned short as_[2][128 * 64];
  __shared__ __align__(16) unsigned short bs_[2][128 * 64];

  const int tid = threadIdx.x;
  const int wid = tid >> 6, lane = tid & 63, l15 = lane & 15, lhi = lane >> 4;
  int m0, n0;
  if (MODE == 0) { m0 = blockIdx.y * 128; n0 = blockIdx.x * 128; }
  else           { m0 = blockIdx.x * 128; n0 = blockIdx.y * 128; }
  const float* Arow = A + (size_t)m0 * 256;
  const float* Brow = Bm + (size_t)n0 * 256;

  const int srow = tid >> 4;      // staging row-within-16
  const int c4 = tid & 15;        // staging float4 column
  float4 ra[8], rb[8];

  auto loadslice = [&](int kc) {
#pragma unroll
    for (int i = 0; i < 8; ++i) {
      int row = i * 16 + srow;
      ra[i] = *(const float4*)(Arow + (size_t)row * 256 + kc * 64 + c4 * 4);
      rb[i] = *(const float4*)(Brow + (size_t)row * 256 + kc * 64 + c4 * 4);
    }
  };
  auto writeslice = [&](int buf) {
#pragma unroll
    for (int i = 0; i < 8; ++i) {
      int row = i * 16 + srow;
      int g = c4 >> 1, half = c4 & 1;
      int off = row * 64 + ((g ^ (row & 7)) << 3) + half * 4;
      *(ushort4*)&as_[buf][off] = pack4(ra[i]);
      *(ushort4*)&bs_[buf][off] = pack4(rb[i]);
    }
  };

  f32x4 acc[2][8];
#pragma unroll
  for (int mt = 0; mt < 2; ++mt)
#pragma unroll
    for (int nt = 0; nt < 8; ++nt) acc[mt][nt] = (f32x4){0.f, 0.f, 0.f, 0.f};

  loadslice(0);
  writeslice(0);
  int cur = 0;
  for (int kc = 0; kc < 4; ++kc) {
    __syncthreads();
    if (kc < 3) loadslice(kc + 1);
#pragma unroll
    for (int ks = 0; ks < 2; ++ks) {
      short8 af[2];
#pragma unroll
      for (int mt = 0; mt < 2; ++mt) {
        int row = wid * 32 + mt * 16 + l15;
        int g = ks * 4 + lhi;
        af[mt] = *(const short8*)&as_[cur][row * 64 + ((g ^ (row & 7)) << 3)];
      }
#pragma unroll
      for (int nt = 0; nt < 8; ++nt) {
        int row = nt * 16 + l15;
        int g = ks * 4 + lhi;
        short8 bf = *(const short8*)&bs_[cur][row * 64 + ((g ^ (row & 7)) << 3)];
        acc[0][nt] = MFMA16(af[0], bf, acc[0][nt]);
        acc[1][nt] = MFMA16(af[1], bf, acc[1][nt]);
      }
    }
    if (kc < 3) writeslice(cur ^ 1);
    cur ^= 1;
  }

  const float QSC = 0.0901684400555602f;  // log2(e)/16
#pragma unroll
  for (int nt = 0; nt < 8; ++nt) {
    if (MODE == 0) {
      int e = n0 + nt * 16 + l15;
      float bv = bias[e];
#pragma unroll
      for (int mt = 0; mt < 2; ++mt)
#pragma unroll
        for (int r = 0; r < 4; ++r) {
          int tok = m0 + wid * 32 + mt * 16 + lhi * 4 + r;
          float val = acc[mt][nt][r] + bv;
          if (e < 256) Qs[(size_t)tok * 256 + e] = f2bf(val * QSC);
          else         Kb[(size_t)tok * 256 + (e - 256)] = f2bf(val);
        }
    } else {
      int tok = n0 + nt * 16 + l15;
      int bb = tok >> 12, n = tok & 4095;
#pragma unroll
      for (int mt = 0; mt < 2; ++mt)
#pragma unroll
        for (int r = 0; r < 4; ++r) {
          int d = m0 + wid * 32 + mt * 16 + lhi * 4 + r;
          float val = acc[mt][nt][r] + bias[512 + d];
          VT[(size_t)bb * (256 * 4096) + (size_t)d * 4096 + n] = f2bf(val);
        }
    }
  }
}

// --------------------------- Flash attention ------------------------------
// Grid 256 = 8 batches * 32 q-blocks (batch = blk&7 -> XCD pin, KV L2-resident).
// Block: 4 waves * 32 q-rows = QB 128; KV tiles of 32, double-buffered LDS.
// LDS = 32+32+8 = 72KB -> 2 blocks/CU; VGPR<=256 -> 2 waves/SIMD (TLP restored).
__global__ __launch_bounds__(256, 2)
void attn_kernel(const unsigned short* __restrict__ Qs,
                 const unsigned short* __restrict__ Kb,
                 const unsigned short* __restrict__ VT,
                 float* __restrict__ out) {
  __shared__ __align__(16) unsigned short lds_k[2 * 32 * 256];   // 32KB
  __shared__ __align__(16) unsigned short lds_vt[2 * 256 * 32];  // 32KB
  __shared__ __align__(16) unsigned short lds_p[4 * 32 * 32];    // 8KB

  const int tid = threadIdx.x;
  const int wid = tid >> 6, lane = tid & 63, l15 = lane & 15, lhi = lane >> 4;
  const int blk = blockIdx.x;
  const int b = blk & 7;
  const int qblk = blk >> 3;                 // 0..31
  const int q0 = qblk * 128 + wid * 32;

  // Q fragments [mt][ks], held all kernel: Q[q=l15][k contig]
  short8 qf[2][8];
#pragma unroll
  for (int mt = 0; mt < 2; ++mt) {
    const unsigned short* qptr =
        Qs + ((size_t)b * 4096 + q0 + mt * 16 + l15) * 256 + lhi * 8;
#pragma unroll
    for (int ks = 0; ks < 8; ++ks) qf[mt][ks] = *(const short8*)(qptr + ks * 32);
  }

  f32x4 acco[2][16];
#pragma unroll
  for (int mt = 0; mt < 2; ++mt)
#pragma unroll
    for (int dt = 0; dt < 16; ++dt) acco[mt][dt] = (f32x4){0.f, 0.f, 0.f, 0.f};
  float m_run[2][4], l_run[2][4];
#pragma unroll
  for (int mt = 0; mt < 2; ++mt)
#pragma unroll
    for (int r = 0; r < 4; ++r) { m_run[mt][r] = -1e30f; l_run[mt][r] = 0.f; }

  const unsigned short* kbase = Kb + (size_t)b * 4096 * 256;
  const unsigned short* vtb   = VT + (size_t)b * 256 * 4096;

  // stage KVB=32 tile: K 16KB (1024 granules), VT 16KB (1024 granules)
  auto stage = [&](int kv0, int buf) {
    unsigned short* kbuf = lds_k + buf * 8192;
    unsigned short* vbuf = lds_vt + buf * 8192;
    const unsigned short* src = kbase + (size_t)kv0 * 256;
#pragma unroll
    for (int i = 0; i < 4; ++i) {
      int g = i * 256 + tid;                  // granule 0..1023
      int row = g >> 5, cp = g & 31;          // K rows of 512B = 32 granules
      int sg = (row << 5) | (cp ^ (row & 7));
      gload_lds16(src + sg * 8, kbuf + (i * 256 + (wid << 6)) * 8);
    }
#pragma unroll
    for (int i = 0; i < 4; ++i) {
      int g = i * 256 + tid;
      int d = g >> 2, cp = g & 3;             // VT rows of 64B = 4 granules
      int sc = cp ^ (d & 3);
      gload_lds16(vtb + (size_t)d * 4096 + kv0 + sc * 8,
                  vbuf + (i * 256 + (wid << 6)) * 8);
    }
  };

  stage(0, 0);
  int cur = 0;
  for (int kv = 0; kv < 128; ++kv) {
    __syncthreads();   // vmcnt(0) drain: buf[cur] staged; buf[cur^1] readers done
    if (kv < 127) stage((kv + 1) * 32, cur ^ 1);
    const unsigned short* kb = lds_k + cur * 8192;
    const unsigned short* vb = lds_vt + cur * 8192;

    // ---- S = Q·K^T (scale folded into Q) ----
    f32x4 accs[2][2];
#pragma unroll
    for (int mt = 0; mt < 2; ++mt)
#pragma unroll
      for (int tt = 0; tt < 2; ++tt) accs[mt][tt] = (f32x4){0.f, 0.f, 0.f, 0.f};
#pragma unroll
    for (int ks = 0; ks < 8; ++ks) {
#pragma unroll
      for (int tt = 0; tt < 2; ++tt) {
        int krow = tt * 16 + l15;
        int c = ks * 4 + lhi;                 // granule 0..31 within 512B row
        short8 kf = *(const short8*)&kb[krow * 256 + ((c ^ (krow & 7)) << 3)];
        accs[0][tt] = MFMA16(qf[0][ks], kf, accs[0][tt]);
        accs[1][tt] = MFMA16(qf[1][ks], kf, accs[1][tt]);
      }
    }

    // ---- online softmax (DPP row reductions; defer-max THR=4 log2-units) ----
    float al[2][4];
    bool resc = false;
#pragma unroll
    for (int mt = 0; mt < 2; ++mt)
#pragma unroll
      for (int r = 0; r < 4; ++r) {
        float mx = fmaxf(accs[mt][0][r], accs[mt][1][r]);
        mx = red16_max(mx);
        float mo = m_run[mt][r];
        float mn = (mx > mo + 4.0f) ? mx : mo;
        al[mt][r] = __builtin_amdgcn_exp2f(mo - mn);
        m_run[mt][r] = mn;
        float rs = 0.f;
#pragma unroll
        for (int tt = 0; tt < 2; ++tt) {
          float p = __builtin_amdgcn_exp2f(accs[mt][tt][r] - mn);
          accs[mt][tt][r] = p;
          rs += p;
        }
        rs = red16_sum(rs);
        l_run[mt][r] = l_run[mt][r] * al[mt][r] + rs;
        resc |= (mn != mo);
      }
    if (__any(resc)) {
#pragma unroll
      for (int mt = 0; mt < 2; ++mt)
#pragma unroll
        for (int dt = 0; dt < 16; ++dt)
#pragma unroll
          for (int r = 0; r < 4; ++r) acco[mt][dt][r] *= al[mt][r];
    }

    // ---- P -> per-wave LDS [32 q][32 k], rows 64B = 4 granules, swizzled ----
#pragma unroll
    for (int mt = 0; mt < 2; ++mt)
#pragma unroll
      for (int tt = 0; tt < 2; ++tt) {
        int cg = tt * 2 + (l15 >> 3);         // col granule of col = tt*16+l15
        int cl = l15 & 7;
#pragma unroll
        for (int r = 0; r < 4; ++r) {
          int q = mt * 16 + lhi * 4 + r;
          lds_p[wid * 1024 + q * 32 + ((cg ^ (q & 3)) << 3) + cl] =
              f2bf(accs[mt][tt][r]);
        }
      }

    // ---- PV: k=32 in one MFMA step; each V fragment feeds 2 MFMAs ----
    {
      int swl = (lhi ^ (l15 & 3)) << 3;
      short8 pf0 = *(const short8*)&lds_p[wid * 1024 + l15 * 32 + swl];
      short8 pf1 = *(const short8*)&lds_p[wid * 1024 + (16 + l15) * 32 + swl];
#pragma unroll
      for (int dt = 0; dt < 16; ++dt) {
        int d = dt * 16 + l15;
        short8 vf = *(const short8*)&vb[d * 32 + ((lhi ^ (d & 3)) << 3)];
        acco[0][dt] = MFMA16(pf0, vf, acco[0][dt]);
        acco[1][dt] = MFMA16(pf1, vf, acco[1][dt]);
      }
    }
    cur ^= 1;
  }

  float inv[2][4];
#pragma unroll
  for (int mt = 0; mt < 2; ++mt)
#pragma unroll
    for (int r = 0; r < 4; ++r) inv[mt][r] = 1.f / l_run[mt][r];
  float* orow = out + ((size_t)b * 4096 + q0) * 256;
#pragma unroll
  for (int mt = 0; mt < 2; ++mt)
#pragma unroll
    for (int dt = 0; dt < 16; ++dt)
#pragma unroll
      for (int r = 0; r < 4; ++r)
        orow[(size_t)(mt * 16 + lhi * 4 + r) * 256 + dt * 16 + l15] =
            acco[mt][dt][r] * inv[mt][r];
}

// ---------------------------------------------------------------------------
extern "C" void kernel_launch(void* const* d_in, const int* in_sizes, int n_in,
                              void* d_out, int out_size, void* d_ws, size_t ws_size,
                              hipStream_t stream) {
  const float* x    = (const float*)d_in[0];   // [8,4096,256]
  const float* W    = (const float*)d_in[1];   // [768,256]
  const float* bias = (const float*)d_in[2];   // [768]
  float* out = (float*)d_out;                  // [8,4096,256] f32

  char* ws = (char*)d_ws;
  unsigned short* Qs = (unsigned short*)(ws);
  unsigned short* Kb = (unsigned short*)(ws + (size_t)16 * 1024 * 1024);
  unsigned short* VT = (unsigned short*)(ws + (size_t)32 * 1024 * 1024);

  proj_kernel<0><<<dim3(4, 256), 256, 0, stream>>>(x, W, bias, Qs, Kb, VT);
  proj_kernel<1><<<dim3(2, 256), 256, 0, stream>>>(W + 512 * 256, x, bias, Qs, Kb, VT);
  attn_kernel<<<256, 256, 0, stream>>>(Qs, Kb, VT, out);
}

// Round 7
// 251.811 us; speedup vs baseline: 2.4636x; 2.4636x over previous
//
#include <hip/hip_runtime.h>
#include <hip/hip_bf16.h>

// ---------------------------------------------------------------------------
// Fused self-attention, B=8 N=4096 D=256, f32 in/out, bf16 MFMA internally.
// ws: Qs bf16 [B*N][256] @0       (pre-scaled by log2e/16)
//     Kb bf16 [B*N][256] @16MB
//     VT bf16 [B][256][N] @32MB   (columns permuted per 16-block: 4-7 <-> 8-11,
//                                  matching the native P-fragment kv order)
// Attn: 512-thread blocks = 4 q-groups x 2 kv-halves; in-block LDS merge.
// ---------------------------------------------------------------------------

typedef __attribute__((ext_vector_type(8))) short short8;    // 8 bf16
typedef __attribute__((ext_vector_type(4))) float f32x4;
typedef __attribute__((ext_vector_type(16))) float f32x16;

#define MFMA16(A, B, C) __builtin_amdgcn_mfma_f32_16x16x32_bf16(A, B, C, 0, 0, 0)
#define MFMA32(A, B, C) __builtin_amdgcn_mfma_f32_32x32x16_bf16(A, B, C, 0, 0, 0)

__device__ __forceinline__ unsigned short f2bf(float f) {
  union { float f; unsigned u; } v; v.f = f;
  unsigned r = v.u + 0x7FFFu + ((v.u >> 16) & 1u);   // RNE
  return (unsigned short)(r >> 16);
}

__device__ __forceinline__ ushort4 pack4(float4 v) {
  ushort4 r;
  r.x = f2bf(v.x); r.y = f2bf(v.y); r.z = f2bf(v.z); r.w = f2bf(v.w);
  return r;
}

__device__ __forceinline__ unsigned packbf2(float a, float b) {
  union { __hip_bfloat162 b2; unsigned u; } cv;
  cv.b2 = __float22bfloat162_rn(make_float2(a, b));
  return cv.u;
}

__device__ __forceinline__ void gload_lds16(const void* g, void* l) {
  __builtin_amdgcn_global_load_lds(
      (const __attribute__((address_space(1))) void*)g,
      (__attribute__((address_space(3))) void*)l, 16, 0, 0);
}

// --------------------------- Projection GEMM (R3/R4-verified) -------------
template <int MODE>
__global__ __launch_bounds__(256)
void proj_kernel(const float* __restrict__ A, const float* __restrict__ Bm,
                 const float* __restrict__ bias,
                 unsigned short* __restrict__ Qs, unsigned short* __restrict__ Kb,
                 unsigned short* __restrict__ VT) {
  __shared__ __align__(16) unsigned short as_[2][128 * 64];
  __shared__ __align__(16) unsigned short bs_[2][128 * 64];

  const int tid = threadIdx.x;
  const int wid = tid >> 6, lane = tid & 63, l15 = lane & 15, lhi = lane >> 4;
  int m0, n0;
  if (MODE == 0) { m0 = blockIdx.y * 128; n0 = blockIdx.x * 128; }
  else           { m0 = blockIdx.x * 128; n0 = blockIdx.y * 128; }
  const float* Arow = A + (size_t)m0 * 256;
  const float* Brow = Bm + (size_t)n0 * 256;

  const int srow = tid >> 4;
  const int c4 = tid & 15;
  float4 ra[8], rb[8];

  auto loadslice = [&](int kc) {
#pragma unroll
    for (int i = 0; i < 8; ++i) {
      int row = i * 16 + srow;
      ra[i] = *(const float4*)(Arow + (size_t)row * 256 + kc * 64 + c4 * 4);
      rb[i] = *(const float4*)(Brow + (size_t)row * 256 + kc * 64 + c4 * 4);
    }
  };
  auto writeslice = [&](int buf) {
#pragma unroll
    for (int i = 0; i < 8; ++i) {
      int row = i * 16 + srow;
      int g = c4 >> 1, half = c4 & 1;
      int off = row * 64 + ((g ^ (row & 7)) << 3) + half * 4;
      *(ushort4*)&as_[buf][off] = pack4(ra[i]);
      *(ushort4*)&bs_[buf][off] = pack4(rb[i]);
    }
  };

  f32x4 acc[2][8];
#pragma unroll
  for (int mt = 0; mt < 2; ++mt)
#pragma unroll
    for (int nt = 0; nt < 8; ++nt) acc[mt][nt] = (f32x4){0.f, 0.f, 0.f, 0.f};

  loadslice(0);
  writeslice(0);
  int cur = 0;
  for (int kc = 0; kc < 4; ++kc) {
    __syncthreads();
    if (kc < 3) loadslice(kc + 1);
#pragma unroll
    for (int ks = 0; ks < 2; ++ks) {
      short8 af[2];
#pragma unroll
      for (int mt = 0; mt < 2; ++mt) {
        int row = wid * 32 + mt * 16 + l15;
        int g = ks * 4 + lhi;
        af[mt] = *(const short8*)&as_[cur][row * 64 + ((g ^ (row & 7)) << 3)];
      }
#pragma unroll
      for (int nt = 0; nt < 8; ++nt) {
        int row = nt * 16 + l15;
        int g = ks * 4 + lhi;
        short8 bf = *(const short8*)&bs_[cur][row * 64 + ((g ^ (row & 7)) << 3)];
        acc[0][nt] = MFMA16(af[0], bf, acc[0][nt]);
        acc[1][nt] = MFMA16(af[1], bf, acc[1][nt]);
      }
    }
    if (kc < 3) writeslice(cur ^ 1);
    cur ^= 1;
  }

  const float QSC = 0.0901684400555602f;  // log2(e)/16
#pragma unroll
  for (int nt = 0; nt < 8; ++nt) {
    if (MODE == 0) {
      int e = n0 + nt * 16 + l15;
      float bv = bias[e];
#pragma unroll
      for (int mt = 0; mt < 2; ++mt)
#pragma unroll
        for (int r = 0; r < 4; ++r) {
          int tok = m0 + wid * 32 + mt * 16 + lhi * 4 + r;
          float val = acc[mt][nt][r] + bv;
          if (e < 256) Qs[(size_t)tok * 256 + e] = f2bf(val * QSC);
          else         Kb[(size_t)tok * 256 + (e - 256)] = f2bf(val);
        }
    } else {
      int tok = n0 + nt * 16 + l15;
      int bb = tok >> 12, n = tok & 4095;
      // column involution within each 16-block: quads 1<->2, so VT' slot
      // order matches the native P-fragment kv order (crow8) in attn.
      int t4 = n & 15;
      int flip = ((t4 >> 2) ^ (t4 >> 3)) & 1;
      int n2 = (n & ~15) | (t4 ^ (flip ? 12 : 0));
#pragma unroll
      for (int mt = 0; mt < 2; ++mt)
#pragma unroll
        for (int r = 0; r < 4; ++r) {
          int d = m0 + wid * 32 + mt * 16 + lhi * 4 + r;
          float val = acc[mt][nt][r] + bias[512 + d];
          VT[(size_t)bb * (256 * 4096) + (size_t)d * 4096 + n2] = f2bf(val);
        }
    }
  }
}

// --------------------------- Flash attention ------------------------------
// Grid 256 = 8 batch * 32 q-blocks, 512 threads = 8 waves:
//   wave = (hv = wid>>2 kv-half) x (qg = wid&3 q-group of 32 rows).
// Swapped QK^T (A=K_lds, B=Q_regs): lane owns q=lane&31 for S/softmax;
// acco rows are q' = crow(r,h) -> per-row scales transported via __shfl.
// KVB=32, double-buffered per half; in-block LDS merge of the two halves.
__global__ __launch_bounds__(512, 2)
void attn_kernel(const unsigned short* __restrict__ Qs,
                 const unsigned short* __restrict__ Kb,
                 const unsigned short* __restrict__ VT,
                 float* __restrict__ out) {
  // [half][buf][ K 8192 shorts | V 8192 shorts ] = 128KB
  __shared__ __align__(16) unsigned short lds_kv[2][2][16384];
  __shared__ float2 lds_ml[8][32];   // 2KB

  const int tid = threadIdx.x;
  const int wid = tid >> 6, lane = tid & 63, l31 = lane & 31, h = lane >> 5;
  const int hv = wid >> 2;           // kv half
  const int qg = wid & 3;            // q group
  const int tid_h = tid & 255;       // thread within half
  const int blk = blockIdx.x;
  const int b = blk & 7;
  const int qblk = blk >> 3;         // 0..31
  const int q0 = qblk * 128 + qg * 32;

  // Q B-frags: lane holds q = l31, k = ks*16 + h*8 + e
  const unsigned short* qp = Qs + ((size_t)b * 4096 + q0 + l31) * 256 + h * 8;
  short8 qf[16];
#pragma unroll
  for (int ks = 0; ks < 16; ++ks) qf[ks] = *(const short8*)(qp + ks * 16);

  f32x16 acco[8];
#pragma unroll
  for (int dt = 0; dt < 8; ++dt)
#pragma unroll
    for (int j = 0; j < 16; ++j) acco[dt][j] = 0.f;
  float m = -1e30f, lsum = 0.f;

  const unsigned short* kbase = Kb + (size_t)b * 4096 * 256;
  const unsigned short* vtb   = VT + (size_t)b * 256 * 4096;

  auto stage = [&](int it, int buf) {
    const int kv0 = hv * 2048 + it * 32;
    unsigned short* kbuf = &lds_kv[hv][buf][0];
    unsigned short* vbuf = &lds_kv[hv][buf][8192];
    const unsigned short* ksrc = kbase + (size_t)kv0 * 256;
#pragma unroll
    for (int i = 0; i < 4; ++i) {
      int g = i * 256 + tid_h;              // K granule: 32 rows x 32
      int row = g >> 5, cp = g & 31;
      int sg = (row << 5) | (cp ^ (row & 7));
      gload_lds16(ksrc + sg * 8, kbuf + (i * 256 + (qg << 6)) * 8);
    }
#pragma unroll
    for (int i = 0; i < 4; ++i) {
      int g = i * 256 + tid_h;              // V granule: 256 rows x 4
      int d = g >> 2, cp = g & 3;
      int sc = cp ^ (d & 3);
      gload_lds16(vtb + (size_t)d * 4096 + kv0 + sc * 8,
                  vbuf + (i * 256 + (qg << 6)) * 8);
    }
  };

  stage(0, 0);
  int cur = 0;
  for (int it = 0; it < 64; ++it) {
    __syncthreads();   // drains own gloads; prev readers of buf cur^1 done
    if (it < 63) stage(it + 1, cur ^ 1);
    const unsigned short* kb = &lds_kv[hv][cur][0];
    const unsigned short* vb = &lds_kv[hv][cur][8192];

    // ---- S^T = K·Q^T: lane holds col q=l31, rows kv=crow(r,h) ----
    f32x16 s0;
#pragma unroll
    for (int j = 0; j < 16; ++j) s0[j] = 0.f;
#pragma unroll
    for (int ks = 0; ks < 16; ++ks) {
      const short8 kf =
          *(const short8*)&kb[l31 * 256 + (((2 * ks + h) ^ (l31 & 7)) << 3)];
      s0 = MFMA32(kf, qf[ks], s0);
    }

    // ---- in-register online softmax for q = l31 ----
    float mx = s0[0];
#pragma unroll
    for (int r = 1; r < 16; ++r) mx = fmaxf(mx, s0[r]);
    mx = fmaxf(mx, __shfl_xor(mx, 32));
    const float mo = m;
    const float mn = (mx > mo + 4.f) ? mx : mo;   // defer-max THR=4
    const float al = __builtin_amdgcn_exp2f(mo - mn);
    m = mn;
    if (__any(mn != mo)) {
      // acco rows are q' = crow(r,h): transport per-row scale via bpermute
      float alq[16];
#pragma unroll
      for (int r = 0; r < 16; ++r)
        alq[r] = __shfl(al, (r & 3) + 8 * (r >> 2) + 4 * h, 64);
#pragma unroll
      for (int dt = 0; dt < 8; ++dt)
#pragma unroll
        for (int r = 0; r < 16; ++r) acco[dt][r] *= alq[r];
    }

    // ---- P = exp2(S - mn) in place; pack native (kv = crow order) ----
    float rs = 0.f;
#pragma unroll
    for (int r = 0; r < 16; ++r) {
      s0[r] = __builtin_amdgcn_exp2f(s0[r] - mn);
      rs += s0[r];
    }
    rs += __shfl_xor(rs, 32);
    lsum = lsum * al + rs;

    short8 pf[2];
    {
      union { unsigned u[4]; short8 v; } a0, a1;
#pragma unroll
      for (int k2 = 0; k2 < 4; ++k2) {
        a0.u[k2] = packbf2(s0[2 * k2], s0[2 * k2 + 1]);
        a1.u[k2] = packbf2(s0[8 + 2 * k2], s0[9 + 2 * k2]);
      }
      pf[0] = a0.v; pf[1] = a1.v;
    }

    // ---- PV: O[q'][d] += P·V; VT' pre-permuted to match pf slots ----
#pragma unroll
    for (int ks = 0; ks < 2; ++ks) {
#pragma unroll
      for (int dt = 0; dt < 8; ++dt) {
        const int d = dt * 32 + l31;
        const short8 vf =
            *(const short8*)&vb[d * 32 + (((2 * ks + h) ^ (l31 & 3)) << 3)];
        acco[dt] = MFMA32(pf[ks], vf, acco[dt]);
      }
    }
    cur ^= 1;
  }

  // ---- in-block merge of the two kv halves (reuse tile LDS) ----
  __syncthreads();   // last compute done; safe to alias tiles
  if (lane < 32) lds_ml[wid][lane] = make_float2(m, lsum);
  float* o_base = (float*)&lds_kv[0][0][0];
  if (hv == 1) {
    float* o = o_base + qg * 8192;     // [32 q'][256 d] f32
#pragma unroll
    for (int dt = 0; dt < 8; ++dt)
#pragma unroll
      for (int r = 0; r < 16; ++r) {
        int qp = (r & 3) + 8 * (r >> 2) + 4 * h;
        o[qp * 256 + dt * 32 + l31] = acco[dt][r];
      }
  }
  __syncthreads();
  if (hv == 0) {
    float* o = o_base + qg * 8192;
    float* orow = out + ((size_t)b * 4096 + q0) * 256;
#pragma unroll
    for (int r = 0; r < 16; ++r) {
      int qp = (r & 3) + 8 * (r >> 2) + 4 * h;
      float2 s_own = lds_ml[wid][qp];
      float2 s_par = lds_ml[wid + 4][qp];
      float mM = fmaxf(s_own.x, s_par.x);
      float w0 = __builtin_amdgcn_exp2f(s_own.x - mM);
      float w1 = __builtin_amdgcn_exp2f(s_par.x - mM);
      float inv = 1.f / (w0 * s_own.y + w1 * s_par.y);
#pragma unroll
      for (int dt = 0; dt < 8; ++dt) {
        float val = (acco[dt][r] * w0 + o[qp * 256 + dt * 32 + l31] * w1) * inv;
        orow[(size_t)qp * 256 + dt * 32 + l31] = val;
      }
    }
  }
}

// ---------------------------------------------------------------------------
extern "C" void kernel_launch(void* const* d_in, const int* in_sizes, int n_in,
                              void* d_out, int out_size, void* d_ws, size_t ws_size,
                              hipStream_t stream) {
  const float* x    = (const float*)d_in[0];   // [8,4096,256]
  const float* W    = (const float*)d_in[1];   // [768,256]
  const float* bias = (const float*)d_in[2];   // [768]
  float* out = (float*)d_out;                  // [8,4096,256] f32

  char* ws = (char*)d_ws;
  unsigned short* Qs = (unsigned short*)(ws);
  unsigned short* Kb = (unsigned short*)(ws + (size_t)16 * 1024 * 1024);
  unsigned short* VT = (unsigned short*)(ws + (size_t)32 * 1024 * 1024);

  proj_kernel<0><<<dim3(4, 256), 256, 0, stream>>>(x, W, bias, Qs, Kb, VT);
  proj_kernel<1><<<dim3(2, 256), 256, 0, stream>>>(W + 512 * 256, x, bias, Qs, Kb, VT);
  attn_kernel<<<256, 512, 0, stream>>>(Qs, Kb, VT, out);
}

// Round 8
// 241.176 us; speedup vs baseline: 2.5723x; 1.0441x over previous
//
#include <hip/hip_runtime.h>
#include <hip/hip_bf16.h>

// ---------------------------------------------------------------------------
// Fused self-attention, B=8 N=4096 D=256, f32 in/out, bf16 MFMA internally.
// ws: Qs bf16 [B*N][256] @0       (pre-scaled by log2e/16)
//     Kb bf16 [B*N][256] @16MB
//     VT bf16 [B][256][N] @32MB   (columns permuted per 16-block: 4-7 <-> 8-11,
//                                  matching the native P-fragment kv order)
// Attn: 512-thread blocks = 4 q-groups x 2 kv-halves; in-block LDS merge.
// R8 change: V LDS swizzle sigma(d) = (d>>1)&3 (was d&3) -> V-reads hit 8
// distinct bank slots per 8 consecutive lanes (was 4) = structural only.
// ---------------------------------------------------------------------------

typedef __attribute__((ext_vector_type(8))) short short8;    // 8 bf16
typedef __attribute__((ext_vector_type(4))) float f32x4;
typedef __attribute__((ext_vector_type(16))) float f32x16;

#define MFMA16(A, B, C) __builtin_amdgcn_mfma_f32_16x16x32_bf16(A, B, C, 0, 0, 0)
#define MFMA32(A, B, C) __builtin_amdgcn_mfma_f32_32x32x16_bf16(A, B, C, 0, 0, 0)

__device__ __forceinline__ unsigned short f2bf(float f) {
  union { float f; unsigned u; } v; v.f = f;
  unsigned r = v.u + 0x7FFFu + ((v.u >> 16) & 1u);   // RNE
  return (unsigned short)(r >> 16);
}

__device__ __forceinline__ ushort4 pack4(float4 v) {
  ushort4 r;
  r.x = f2bf(v.x); r.y = f2bf(v.y); r.z = f2bf(v.z); r.w = f2bf(v.w);
  return r;
}

__device__ __forceinline__ unsigned packbf2(float a, float b) {
  union { __hip_bfloat162 b2; unsigned u; } cv;
  cv.b2 = __float22bfloat162_rn(make_float2(a, b));
  return cv.u;
}

__device__ __forceinline__ void gload_lds16(const void* g, void* l) {
  __builtin_amdgcn_global_load_lds(
      (const __attribute__((address_space(1))) void*)g,
      (__attribute__((address_space(3))) void*)l, 16, 0, 0);
}

// --------------------------- Projection GEMM (R3/R4-verified) -------------
template <int MODE>
__global__ __launch_bounds__(256)
void proj_kernel(const float* __restrict__ A, const float* __restrict__ Bm,
                 const float* __restrict__ bias,
                 unsigned short* __restrict__ Qs, unsigned short* __restrict__ Kb,
                 unsigned short* __restrict__ VT) {
  __shared__ __align__(16) unsigned short as_[2][128 * 64];
  __shared__ __align__(16) unsigned short bs_[2][128 * 64];

  const int tid = threadIdx.x;
  const int wid = tid >> 6, lane = tid & 63, l15 = lane & 15, lhi = lane >> 4;
  int m0, n0;
  if (MODE == 0) { m0 = blockIdx.y * 128; n0 = blockIdx.x * 128; }
  else           { m0 = blockIdx.x * 128; n0 = blockIdx.y * 128; }
  const float* Arow = A + (size_t)m0 * 256;
  const float* Brow = Bm + (size_t)n0 * 256;

  const int srow = tid >> 4;
  const int c4 = tid & 15;
  float4 ra[8], rb[8];

  auto loadslice = [&](int kc) {
#pragma unroll
    for (int i = 0; i < 8; ++i) {
      int row = i * 16 + srow;
      ra[i] = *(const float4*)(Arow + (size_t)row * 256 + kc * 64 + c4 * 4);
      rb[i] = *(const float4*)(Brow + (size_t)row * 256 + kc * 64 + c4 * 4);
    }
  };
  auto writeslice = [&](int buf) {
#pragma unroll
    for (int i = 0; i < 8; ++i) {
      int row = i * 16 + srow;
      int g = c4 >> 1, half = c4 & 1;
      int off = row * 64 + ((g ^ (row & 7)) << 3) + half * 4;
      *(ushort4*)&as_[buf][off] = pack4(ra[i]);
      *(ushort4*)&bs_[buf][off] = pack4(rb[i]);
    }
  };

  f32x4 acc[2][8];
#pragma unroll
  for (int mt = 0; mt < 2; ++mt)
#pragma unroll
    for (int nt = 0; nt < 8; ++nt) acc[mt][nt] = (f32x4){0.f, 0.f, 0.f, 0.f};

  loadslice(0);
  writeslice(0);
  int cur = 0;
  for (int kc = 0; kc < 4; ++kc) {
    __syncthreads();
    if (kc < 3) loadslice(kc + 1);
#pragma unroll
    for (int ks = 0; ks < 2; ++ks) {
      short8 af[2];
#pragma unroll
      for (int mt = 0; mt < 2; ++mt) {
        int row = wid * 32 + mt * 16 + l15;
        int g = ks * 4 + lhi;
        af[mt] = *(const short8*)&as_[cur][row * 64 + ((g ^ (row & 7)) << 3)];
      }
#pragma unroll
      for (int nt = 0; nt < 8; ++nt) {
        int row = nt * 16 + l15;
        int g = ks * 4 + lhi;
        short8 bf = *(const short8*)&bs_[cur][row * 64 + ((g ^ (row & 7)) << 3)];
        acc[0][nt] = MFMA16(af[0], bf, acc[0][nt]);
        acc[1][nt] = MFMA16(af[1], bf, acc[1][nt]);
      }
    }
    if (kc < 3) writeslice(cur ^ 1);
    cur ^= 1;
  }

  const float QSC = 0.0901684400555602f;  // log2(e)/16
#pragma unroll
  for (int nt = 0; nt < 8; ++nt) {
    if (MODE == 0) {
      int e = n0 + nt * 16 + l15;
      float bv = bias[e];
#pragma unroll
      for (int mt = 0; mt < 2; ++mt)
#pragma unroll
        for (int r = 0; r < 4; ++r) {
          int tok = m0 + wid * 32 + mt * 16 + lhi * 4 + r;
          float val = acc[mt][nt][r] + bv;
          if (e < 256) Qs[(size_t)tok * 256 + e] = f2bf(val * QSC);
          else         Kb[(size_t)tok * 256 + (e - 256)] = f2bf(val);
        }
    } else {
      int tok = n0 + nt * 16 + l15;
      int bb = tok >> 12, n = tok & 4095;
      // column involution within each 16-block: quads 1<->2, so VT' slot
      // order matches the native P-fragment kv order (crow8) in attn.
      int t4 = n & 15;
      int flip = ((t4 >> 2) ^ (t4 >> 3)) & 1;
      int n2 = (n & ~15) | (t4 ^ (flip ? 12 : 0));
#pragma unroll
      for (int mt = 0; mt < 2; ++mt)
#pragma unroll
        for (int r = 0; r < 4; ++r) {
          int d = m0 + wid * 32 + mt * 16 + lhi * 4 + r;
          float val = acc[mt][nt][r] + bias[512 + d];
          VT[(size_t)bb * (256 * 4096) + (size_t)d * 4096 + n2] = f2bf(val);
        }
    }
  }
}

// --------------------------- Flash attention ------------------------------
// Grid 256 = 8 batch * 32 q-blocks, 512 threads = 8 waves:
//   wave = (hv = wid>>2 kv-half) x (qg = wid&3 q-group of 32 rows).
// Swapped QK^T (A=K_lds, B=Q_regs): lane owns q=lane&31 for S/softmax;
// acco rows are q' = crow(r,h) -> per-row scales transported via __shfl.
// KVB=32, double-buffered per half; in-block LDS merge of the two halves.
__global__ __launch_bounds__(512, 2)
void attn_kernel(const unsigned short* __restrict__ Qs,
                 const unsigned short* __restrict__ Kb,
                 const unsigned short* __restrict__ VT,
                 float* __restrict__ out) {
  // [half][buf][ K 8192 shorts | V 8192 shorts ] = 128KB
  __shared__ __align__(16) unsigned short lds_kv[2][2][16384];
  __shared__ float2 lds_ml[8][32];   // 2KB

  const int tid = threadIdx.x;
  const int wid = tid >> 6, lane = tid & 63, l31 = lane & 31, h = lane >> 5;
  const int hv = wid >> 2;           // kv half
  const int qg = wid & 3;            // q group
  const int tid_h = tid & 255;       // thread within half
  const int blk = blockIdx.x;
  const int b = blk & 7;
  const int qblk = blk >> 3;         // 0..31
  const int q0 = qblk * 128 + qg * 32;

  // Q B-frags: lane holds q = l31, k = ks*16 + h*8 + e
  const unsigned short* qp = Qs + ((size_t)b * 4096 + q0 + l31) * 256 + h * 8;
  short8 qf[16];
#pragma unroll
  for (int ks = 0; ks < 16; ++ks) qf[ks] = *(const short8*)(qp + ks * 16);

  f32x16 acco[8];
#pragma unroll
  for (int dt = 0; dt < 8; ++dt)
#pragma unroll
    for (int j = 0; j < 16; ++j) acco[dt][j] = 0.f;
  float m = -1e30f, lsum = 0.f;

  const unsigned short* kbase = Kb + (size_t)b * 4096 * 256;
  const unsigned short* vtb   = VT + (size_t)b * 256 * 4096;

  auto stage = [&](int it, int buf) {
    const int kv0 = hv * 2048 + it * 32;
    unsigned short* kbuf = &lds_kv[hv][buf][0];
    unsigned short* vbuf = &lds_kv[hv][buf][8192];
    const unsigned short* ksrc = kbase + (size_t)kv0 * 256;
#pragma unroll
    for (int i = 0; i < 4; ++i) {
      int g = i * 256 + tid_h;              // K granule: 32 rows x 32
      int row = g >> 5, cp = g & 31;
      int sg = (row << 5) | (cp ^ (row & 7));
      gload_lds16(ksrc + sg * 8, kbuf + (i * 256 + (qg << 6)) * 8);
    }
#pragma unroll
    for (int i = 0; i < 4; ++i) {
      int g = i * 256 + tid_h;              // V granule: 256 rows x 4
      int d = g >> 2, cp = g & 3;
      int sc = cp ^ ((d >> 1) & 3);         // R8: sigma(d)=(d>>1)&3
      gload_lds16(vtb + (size_t)d * 4096 + kv0 + sc * 8,
                  vbuf + (i * 256 + (qg << 6)) * 8);
    }
  };

  stage(0, 0);
  int cur = 0;
  for (int it = 0; it < 64; ++it) {
    __syncthreads();   // drains own gloads; prev readers of buf cur^1 done
    if (it < 63) stage(it + 1, cur ^ 1);
    const unsigned short* kb = &lds_kv[hv][cur][0];
    const unsigned short* vb = &lds_kv[hv][cur][8192];

    // ---- S^T = K·Q^T: lane holds col q=l31, rows kv=crow(r,h) ----
    f32x16 s0;
#pragma unroll
    for (int j = 0; j < 16; ++j) s0[j] = 0.f;
#pragma unroll
    for (int ks = 0; ks < 16; ++ks) {
      const short8 kf =
          *(const short8*)&kb[l31 * 256 + (((2 * ks + h) ^ (l31 & 7)) << 3)];
      s0 = MFMA32(kf, qf[ks], s0);
    }

    // ---- in-register online softmax for q = l31 ----
    float mx = s0[0];
#pragma unroll
    for (int r = 1; r < 16; ++r) mx = fmaxf(mx, s0[r]);
    mx = fmaxf(mx, __shfl_xor(mx, 32));
    const float mo = m;
    const float mn = (mx > mo + 4.f) ? mx : mo;   // defer-max THR=4
    const float al = __builtin_amdgcn_exp2f(mo - mn);
    m = mn;
    if (__any(mn != mo)) {
      // acco rows are q' = crow(r,h): transport per-row scale via bpermute
      float alq[16];
#pragma unroll
      for (int r = 0; r < 16; ++r)
        alq[r] = __shfl(al, (r & 3) + 8 * (r >> 2) + 4 * h, 64);
#pragma unroll
      for (int dt = 0; dt < 8; ++dt)
#pragma unroll
        for (int r = 0; r < 16; ++r) acco[dt][r] *= alq[r];
    }

    // ---- P = exp2(S - mn) in place; pack native (kv = crow order) ----
    float rs = 0.f;
#pragma unroll
    for (int r = 0; r < 16; ++r) {
      s0[r] = __builtin_amdgcn_exp2f(s0[r] - mn);
      rs += s0[r];
    }
    rs += __shfl_xor(rs, 32);
    lsum = lsum * al + rs;

    short8 pf[2];
    {
      union { unsigned u[4]; short8 v; } a0, a1;
#pragma unroll
      for (int k2 = 0; k2 < 4; ++k2) {
        a0.u[k2] = packbf2(s0[2 * k2], s0[2 * k2 + 1]);
        a1.u[k2] = packbf2(s0[8 + 2 * k2], s0[9 + 2 * k2]);
      }
      pf[0] = a0.v; pf[1] = a1.v;
    }

    // ---- PV: O[q'][d] += P·V; VT' pre-permuted to match pf slots ----
#pragma unroll
    for (int ks = 0; ks < 2; ++ks) {
#pragma unroll
      for (int dt = 0; dt < 8; ++dt) {
        const int d = dt * 32 + l31;
        const short8 vf = *(const short8*)
            &vb[d * 32 + (((2 * ks + h) ^ ((l31 >> 1) & 3)) << 3)];  // R8 sigma
        acco[dt] = MFMA32(pf[ks], vf, acco[dt]);
      }
    }
    cur ^= 1;
  }

  // ---- in-block merge of the two kv halves (reuse tile LDS) ----
  __syncthreads();   // last compute done; safe to alias tiles
  if (lane < 32) lds_ml[wid][lane] = make_float2(m, lsum);
  float* o_base = (float*)&lds_kv[0][0][0];
  if (hv == 1) {
    float* o = o_base + qg * 8192;     // [32 q'][256 d] f32
#pragma unroll
    for (int dt = 0; dt < 8; ++dt)
#pragma unroll
      for (int r = 0; r < 16; ++r) {
        int qp = (r & 3) + 8 * (r >> 2) + 4 * h;
        o[qp * 256 + dt * 32 + l31] = acco[dt][r];
      }
  }
  __syncthreads();
  if (hv == 0) {
    float* o = o_base + qg * 8192;
    float* orow = out + ((size_t)b * 4096 + q0) * 256;
#pragma unroll
    for (int r = 0; r < 16; ++r) {
      int qp = (r & 3) + 8 * (r >> 2) + 4 * h;
      float2 s_own = lds_ml[wid][qp];
      float2 s_par = lds_ml[wid + 4][qp];
      float mM = fmaxf(s_own.x, s_par.x);
      float w0 = __builtin_amdgcn_exp2f(s_own.x - mM);
      float w1 = __builtin_amdgcn_exp2f(s_par.x - mM);
      float inv = 1.f / (w0 * s_own.y + w1 * s_par.y);
#pragma unroll
      for (int dt = 0; dt < 8; ++dt) {
        float val = (acco[dt][r] * w0 + o[qp * 256 + dt * 32 + l31] * w1) * inv;
        orow[(size_t)qp * 256 + dt * 32 + l31] = val;
      }
    }
  }
}

// ---------------------------------------------------------------------------
extern "C" void kernel_launch(void* const* d_in, const int* in_sizes, int n_in,
                              void* d_out, int out_size, void* d_ws, size_t ws_size,
                              hipStream_t stream) {
  const float* x    = (const float*)d_in[0];   // [8,4096,256]
  const float* W    = (const float*)d_in[1];   // [768,256]
  const float* bias = (const float*)d_in[2];   // [768]
  float* out = (float*)d_out;                  // [8,4096,256] f32

  char* ws = (char*)d_ws;
  unsigned short* Qs = (unsigned short*)(ws);
  unsigned short* Kb = (unsigned short*)(ws + (size_t)16 * 1024 * 1024);
  unsigned short* VT = (unsigned short*)(ws + (size_t)32 * 1024 * 1024);

  proj_kernel<0><<<dim3(4, 256), 256, 0, stream>>>(x, W, bias, Qs, Kb, VT);
  proj_kernel<1><<<dim3(2, 256), 256, 0, stream>>>(W + 512 * 256, x, bias, Qs, Kb, VT);
  attn_kernel<<<256, 512, 0, stream>>>(Qs, Kb, VT, out);
}